// Round 1
// baseline (1351.698 us; speedup 1.0000x reference)
//
#include <hip/hip_runtime.h>
#include <cmath>

#define BB   64
#define SEQ  1024
#define DD   256
#define HH   32
#define G4   128   // 4*H
#define VV   2048

__device__ __forceinline__ float sigm(float x) { return 1.0f / (1.0f + expf(-x)); }

// ---------------------------------------------------------------------------
// Kernel A1: emb_proj[v][j] = b_ih1[j] + b_hh1[j] + sum_d emb[v][d] * W_ih1[j][d]
// grid = V blocks, block = 128 threads (one per gate row j)
// ---------------------------------------------------------------------------
__global__ __launch_bounds__(128) void emb_proj_kernel(
    const float* __restrict__ emb, const float* __restrict__ W_ih1,
    const float* __restrict__ b_ih1, const float* __restrict__ b_hh1,
    float* __restrict__ emb_proj)
{
    const int v = blockIdx.x;
    const int j = threadIdx.x;
    __shared__ __align__(16) float ev[DD];
    ev[j]       = emb[v * DD + j];
    ev[j + 128] = emb[v * DD + 128 + j];
    __syncthreads();
    float acc = b_ih1[j] + b_hh1[j];
#pragma unroll 8
    for (int q = 0; q < DD / 4; ++q) {
        float4 w = *(const float4*)&W_ih1[j * DD + 4 * q];
        float4 e = *(const float4*)&ev[4 * q];
        acc += w.x * e.x + w.y * e.y + w.z * e.z + w.w * e.w;
    }
    emb_proj[v * G4 + j] = acc;
}

// ---------------------------------------------------------------------------
// Kernel A2: W_fcT[k][v] = W_fc[v][k]   (V=2048, H=32)
// ---------------------------------------------------------------------------
__global__ __launch_bounds__(256) void transpose_wfc_kernel(
    const float* __restrict__ W_fc, float* __restrict__ W_fcT)
{
    int i = blockIdx.x * 256 + threadIdx.x;  // i < V*H
    int v = i >> 5;
    int k = i & 31;
    W_fcT[k * VV + v] = W_fc[i];
}

// ---------------------------------------------------------------------------
// Kernel B: the 2-layer LSTM recurrence. One block per batch element.
// block = 128 threads: thread j owns gate row j (rows 0-31 i, 32-63 f,
// 64-95 g, 96-127 o). Recurrent weight rows live in registers.
// h/c state and activated gates are in LDS. Writes h2_all[b][t][:].
// ---------------------------------------------------------------------------
__global__ __launch_bounds__(128) void lstm_rec_kernel(
    const int* __restrict__ x_ids, const float* __restrict__ emb_proj,
    const float* __restrict__ W_hh1, const float* __restrict__ W_ih2,
    const float* __restrict__ W_hh2, const float* __restrict__ b_ih2,
    const float* __restrict__ b_hh2, float* __restrict__ h2_all)
{
    const int b = blockIdx.x;
    const int j = threadIdx.x;
    __shared__ __align__(16) float h1s[HH];
    __shared__ __align__(16) float h2s[HH];
    __shared__ __align__(16) float g1[G4];
    __shared__ __align__(16) float g2[G4];

    float whh1[HH], wih2[HH], whh2[HH];
#pragma unroll
    for (int q = 0; q < HH / 4; ++q) {
        float4 a = *(const float4*)&W_hh1[j * HH + 4 * q];
        whh1[4*q] = a.x; whh1[4*q+1] = a.y; whh1[4*q+2] = a.z; whh1[4*q+3] = a.w;
        float4 c = *(const float4*)&W_ih2[j * HH + 4 * q];
        wih2[4*q] = c.x; wih2[4*q+1] = c.y; wih2[4*q+2] = c.z; wih2[4*q+3] = c.w;
        float4 e = *(const float4*)&W_hh2[j * HH + 4 * q];
        whh2[4*q] = e.x; whh2[4*q+1] = e.y; whh2[4*q+2] = e.z; whh2[4*q+3] = e.w;
    }
    const float bias2 = b_ih2[j] + b_hh2[j];
    float c1 = 0.0f, c2 = 0.0f;
    if (j < HH) { h1s[j] = 0.0f; h2s[j] = 0.0f; }
    __syncthreads();

    const int* ids = x_ids + b * SEQ;
    float epj = emb_proj[(long)ids[0] * G4 + j];

    for (int t = 0; t < SEQ; ++t) {
        // prefetch next step's emb_proj row (hidden under this step's work)
        const int tn = (t + 1 < SEQ) ? (t + 1) : t;
        const int idn = ids[tn];
        const float epn = emb_proj[(long)idn * G4 + j];

        // ---- phase 1: layer-1 gates ----
        float g = epj;
#pragma unroll
        for (int q = 0; q < HH / 4; ++q) {
            float4 h = *(const float4*)&h1s[4 * q];
            g += whh1[4*q] * h.x + whh1[4*q+1] * h.y + whh1[4*q+2] * h.z + whh1[4*q+3] * h.w;
        }
        g1[j] = (j >= 64 && j < 96) ? tanhf(g) : sigm(g);
        __syncthreads();

        // ---- phase 2: layer-1 state update ----
        if (j < HH) {
            c1 = g1[HH + j] * c1 + g1[j] * g1[2 * HH + j];
            h1s[j] = g1[3 * HH + j] * tanhf(c1);
        }
        __syncthreads();

        // ---- phase 3: layer-2 gates ----
        float gg = bias2;
#pragma unroll
        for (int q = 0; q < HH / 4; ++q) {
            float4 h  = *(const float4*)&h1s[4 * q];
            gg += wih2[4*q] * h.x + wih2[4*q+1] * h.y + wih2[4*q+2] * h.z + wih2[4*q+3] * h.w;
            float4 h2 = *(const float4*)&h2s[4 * q];
            gg += whh2[4*q] * h2.x + whh2[4*q+1] * h2.y + whh2[4*q+2] * h2.z + whh2[4*q+3] * h2.w;
        }
        g2[j] = (j >= 64 && j < 96) ? tanhf(gg) : sigm(gg);
        __syncthreads();

        // ---- phase 4: layer-2 state update + emit h2 ----
        if (j < HH) {
            c2 = g2[HH + j] * c2 + g2[j] * g2[2 * HH + j];
            float h2n = g2[3 * HH + j] * tanhf(c2);
            h2s[j] = h2n;
            h2_all[((long)b * SEQ + t) * HH + j] = h2n;
        }
        __syncthreads();

        epj = epn;
    }
}

// ---------------------------------------------------------------------------
// Kernel C: logits = h2 @ W_fc^T + b_fc, then row softmax, write [B*S][V].
// One block per 8 rows; 256 threads; thread owns 8 contiguous vocab cols.
// ---------------------------------------------------------------------------
__global__ __launch_bounds__(256) void fc_softmax_kernel(
    const float* __restrict__ h2_all, const float* __restrict__ W_fcT,
    const float* __restrict__ b_fc, float* __restrict__ out)
{
    const int tid = threadIdx.x;
    const long rowbase = (long)blockIdx.x * 8;
    __shared__ __align__(16) float h2t[8][HH];
    __shared__ float wred[8][4];

    h2t[tid >> 5][tid & 31] = h2_all[rowbase * HH + tid];
    __syncthreads();

    const int v0 = tid * 8;
    const float4 bf0 = *(const float4*)&b_fc[v0];
    const float4 bf1 = *(const float4*)&b_fc[v0 + 4];
    float acc[8][8];
#pragma unroll
    for (int r = 0; r < 8; ++r) {
        acc[r][0] = bf0.x; acc[r][1] = bf0.y; acc[r][2] = bf0.z; acc[r][3] = bf0.w;
        acc[r][4] = bf1.x; acc[r][5] = bf1.y; acc[r][6] = bf1.z; acc[r][7] = bf1.w;
    }

#pragma unroll
    for (int kq = 0; kq < 8; ++kq) {
        const int k = kq * 4;
        float4 wa[4], wb[4];
#pragma unroll
        for (int i = 0; i < 4; ++i) {
            wa[i] = *(const float4*)&W_fcT[(k + i) * VV + v0];
            wb[i] = *(const float4*)&W_fcT[(k + i) * VV + v0 + 4];
        }
#pragma unroll
        for (int r = 0; r < 8; ++r) {
            const float4 h = *(const float4*)&h2t[r][k];
            const float hh[4] = {h.x, h.y, h.z, h.w};
#pragma unroll
            for (int i = 0; i < 4; ++i) {
                acc[r][0] += hh[i] * wa[i].x; acc[r][1] += hh[i] * wa[i].y;
                acc[r][2] += hh[i] * wa[i].z; acc[r][3] += hh[i] * wa[i].w;
                acc[r][4] += hh[i] * wb[i].x; acc[r][5] += hh[i] * wb[i].y;
                acc[r][6] += hh[i] * wb[i].z; acc[r][7] += hh[i] * wb[i].w;
            }
        }
    }

    const int wv = tid >> 6;     // wave id
    const int lane = tid & 63;

    // ---- row max (block-wide) ----
    float m[8];
#pragma unroll
    for (int r = 0; r < 8; ++r) {
        float v = acc[r][0];
#pragma unroll
        for (int c = 1; c < 8; ++c) v = fmaxf(v, acc[r][c]);
#pragma unroll
        for (int s = 32; s >= 1; s >>= 1) v = fmaxf(v, __shfl_xor(v, s, 64));
        m[r] = v;
    }
    if (lane == 0) {
#pragma unroll
        for (int r = 0; r < 8; ++r) wred[r][wv] = m[r];
    }
    __syncthreads();
    float rm[8];
#pragma unroll
    for (int r = 0; r < 8; ++r)
        rm[r] = fmaxf(fmaxf(wred[r][0], wred[r][1]), fmaxf(wred[r][2], wred[r][3]));
    __syncthreads();

    // ---- exp + row sum (block-wide) ----
    float s[8];
#pragma unroll
    for (int r = 0; r < 8; ++r) {
        float sum = 0.0f;
#pragma unroll
        for (int c = 0; c < 8; ++c) {
            float e = expf(acc[r][c] - rm[r]);
            acc[r][c] = e;
            sum += e;
        }
#pragma unroll
        for (int st = 32; st >= 1; st >>= 1) sum += __shfl_xor(sum, st, 64);
        s[r] = sum;
    }
    if (lane == 0) {
#pragma unroll
        for (int r = 0; r < 8; ++r) wred[r][wv] = s[r];
    }
    __syncthreads();

#pragma unroll
    for (int r = 0; r < 8; ++r) {
        const float rs = wred[r][0] + wred[r][1] + wred[r][2] + wred[r][3];
        const float inv = 1.0f / rs;
        float4 o0 = make_float4(acc[r][0] * inv, acc[r][1] * inv, acc[r][2] * inv, acc[r][3] * inv);
        float4 o1 = make_float4(acc[r][4] * inv, acc[r][5] * inv, acc[r][6] * inv, acc[r][7] * inv);
        float* op = out + (rowbase + r) * VV + v0;
        *(float4*)op = o0;
        *(float4*)(op + 4) = o1;
    }
}

// ---------------------------------------------------------------------------
extern "C" void kernel_launch(void* const* d_in, const int* in_sizes, int n_in,
                              void* d_out, int out_size, void* d_ws, size_t ws_size,
                              hipStream_t stream)
{
    const int*   x_ids = (const int*)d_in[0];
    const float* emb   = (const float*)d_in[1];
    const float* W_ih1 = (const float*)d_in[2];
    const float* W_hh1 = (const float*)d_in[3];
    const float* b_ih1 = (const float*)d_in[4];
    const float* b_hh1 = (const float*)d_in[5];
    const float* W_ih2 = (const float*)d_in[6];
    const float* W_hh2 = (const float*)d_in[7];
    const float* b_ih2 = (const float*)d_in[8];
    const float* b_hh2 = (const float*)d_in[9];
    const float* W_fc  = (const float*)d_in[10];
    const float* b_fc  = (const float*)d_in[11];
    float* out = (float*)d_out;

    float* ws = (float*)d_ws;
    float* emb_proj = ws;                         // V*4H   = 262144
    float* W_fcT    = ws + 262144;                // H*V    = 65536
    float* h2_all   = ws + 262144 + 65536;        // B*S*H  = 2097152

    emb_proj_kernel<<<VV, 128, 0, stream>>>(emb, W_ih1, b_ih1, b_hh1, emb_proj);
    transpose_wfc_kernel<<<(VV * HH) / 256, 256, 0, stream>>>(W_fc, W_fcT);
    lstm_rec_kernel<<<BB, 128, 0, stream>>>(x_ids, emb_proj, W_hh1, W_ih2, W_hh2,
                                            b_ih2, b_hh2, h2_all);
    fc_softmax_kernel<<<(BB * SEQ) / 8, 256, 0, stream>>>(h2_all, W_fcT, b_fc, out);
}

// Round 2
// 1287.126 us; speedup vs baseline: 1.0502x; 1.0502x over previous
//
#include <hip/hip_runtime.h>
#include <cmath>

#define BB   64
#define SEQ  1024
#define DD   256
#define HH   32
#define G4   128   // 4*H
#define VV   2048

__device__ __forceinline__ float sigm(float x) { return 1.0f / (1.0f + expf(-x)); }

__device__ __forceinline__ float rlane(float v, int k) {
    return __int_as_float(__builtin_amdgcn_readlane(__float_as_int(v), k));
}
// fast sigmoid: 1 - 1/(1+e^x)   (exact form e^x/(1+e^x), monotone, saturates correctly)
__device__ __forceinline__ float fsigm(float x) {
    return 1.0f - __builtin_amdgcn_rcpf(1.0f + __expf(x));
}
// fast tanh: 1 - 2/(1+e^(2x))
__device__ __forceinline__ float ftanh(float x) {
    return 1.0f - 2.0f * __builtin_amdgcn_rcpf(1.0f + __expf(2.0f * x));
}

// ---------------------------------------------------------------------------
// Kernel A1: emb_proj[v][j] = b_ih1[j] + b_hh1[j] + sum_d emb[v][d] * W_ih1[j][d]
// ---------------------------------------------------------------------------
__global__ __launch_bounds__(128) void emb_proj_kernel(
    const float* __restrict__ emb, const float* __restrict__ W_ih1,
    const float* __restrict__ b_ih1, const float* __restrict__ b_hh1,
    float* __restrict__ emb_proj)
{
    const int v = blockIdx.x;
    const int j = threadIdx.x;
    __shared__ __align__(16) float ev[DD];
    ev[j]       = emb[v * DD + j];
    ev[j + 128] = emb[v * DD + 128 + j];
    __syncthreads();
    float acc = b_ih1[j] + b_hh1[j];
#pragma unroll 8
    for (int q = 0; q < DD / 4; ++q) {
        float4 w = *(const float4*)&W_ih1[j * DD + 4 * q];
        float4 e = *(const float4*)&ev[4 * q];
        acc += w.x * e.x + w.y * e.y + w.z * e.z + w.w * e.w;
    }
    emb_proj[v * G4 + j] = acc;
}

// ---------------------------------------------------------------------------
// Kernel A2: W_fcT[k][v] = W_fc[v][k]
// ---------------------------------------------------------------------------
__global__ __launch_bounds__(256) void transpose_wfc_kernel(
    const float* __restrict__ W_fc, float* __restrict__ W_fcT)
{
    int i = blockIdx.x * 256 + threadIdx.x;
    int v = i >> 5;
    int k = i & 31;
    W_fcT[k * VV + v] = W_fc[i];
}

// ---------------------------------------------------------------------------
// Kernel B: 2-layer LSTM recurrence, ONE WAVE per batch element, no LDS,
// no barriers. Lane l owns gate rows r0=l and r1=l+64.
//   rows 0-31: i   rows 32-63: f   rows 64-95: g   rows 96-127: o
// Lane half 0 (l<32) holds (i,g) of unit l; half 1 holds (f,o) of unit l-32.
// Cross-half exchange via shfl_xor(32); h broadcast via readlane->SGPR
// consumed directly as v_fmac scalar operand.
// ---------------------------------------------------------------------------
__global__ __launch_bounds__(64, 1) void lstm_rec_wave_kernel(
    const int* __restrict__ x_ids, const float* __restrict__ emb_proj,
    const float* __restrict__ W_hh1, const float* __restrict__ W_ih2,
    const float* __restrict__ W_hh2, const float* __restrict__ b_ih2,
    const float* __restrict__ b_hh2, float* __restrict__ h2_all)
{
    const int b = blockIdx.x;
    const int l = threadIdx.x;      // 0..63
    const int half = l >> 5;
    const int r0 = l;
    const int r1 = l + 64;

    // r0 rows (i or f) are always sigmoid; r1 rows: g (tanh) on half0, o (sigm) on half1
    const float a1 = half ? 1.0f : 2.0f;   // exp argument scale
    const float c1p = half ? 1.0f : 2.0f;  // rcp coefficient

    float whh1_0[HH], whh1_1[HH], wih2_0[HH], wih2_1[HH], whh2_0[HH], whh2_1[HH];
#pragma unroll
    for (int q = 0; q < HH / 4; ++q) {
        float4 x;
        x = *(const float4*)&W_hh1[r0 * HH + 4 * q];
        whh1_0[4*q]=x.x; whh1_0[4*q+1]=x.y; whh1_0[4*q+2]=x.z; whh1_0[4*q+3]=x.w;
        x = *(const float4*)&W_hh1[r1 * HH + 4 * q];
        whh1_1[4*q]=x.x; whh1_1[4*q+1]=x.y; whh1_1[4*q+2]=x.z; whh1_1[4*q+3]=x.w;
        x = *(const float4*)&W_ih2[r0 * HH + 4 * q];
        wih2_0[4*q]=x.x; wih2_0[4*q+1]=x.y; wih2_0[4*q+2]=x.z; wih2_0[4*q+3]=x.w;
        x = *(const float4*)&W_ih2[r1 * HH + 4 * q];
        wih2_1[4*q]=x.x; wih2_1[4*q+1]=x.y; wih2_1[4*q+2]=x.z; wih2_1[4*q+3]=x.w;
        x = *(const float4*)&W_hh2[r0 * HH + 4 * q];
        whh2_0[4*q]=x.x; whh2_0[4*q+1]=x.y; whh2_0[4*q+2]=x.z; whh2_0[4*q+3]=x.w;
        x = *(const float4*)&W_hh2[r1 * HH + 4 * q];
        whh2_1[4*q]=x.x; whh2_1[4*q+1]=x.y; whh2_1[4*q+2]=x.z; whh2_1[4*q+3]=x.w;
    }
    const float bias20 = b_ih2[r0] + b_hh2[r0];
    const float bias21 = b_ih2[r1] + b_hh2[r1];

    const int* ids = x_ids + b * SEQ;
    float c1 = 0.0f, c2 = 0.0f;
    float h1_own = 0.0f, h2_own = 0.0f;

    int id0 = ids[0];
    int idn = ids[1];
    float ep0 = emb_proj[id0 * G4 + r0];
    float ep1 = emb_proj[id0 * G4 + r1];

    float* h2out = h2_all + (long)b * SEQ * HH + l;

    for (int t = 0; t < SEQ; ++t) {
        // prefetch next step's emb_proj row + id two steps ahead
        const float ep0n = emb_proj[idn * G4 + r0];
        const float ep1n = emb_proj[idn * G4 + r1];
        const int tn2 = (t + 2 < SEQ) ? (t + 2) : (SEQ - 1);
        const int idn2 = ids[tn2];

        // ---- layer 1 gates: ep + W_hh1 @ h1 ----
        float g0a = 0.0f, g0b = 0.0f, g1a = 0.0f, g1b = 0.0f;
#pragma unroll
        for (int k = 0; k < 16; ++k) {
            const float hk = rlane(h1_own, k);
            g0a += hk * whh1_0[k];
            g1a += hk * whh1_1[k];
        }
#pragma unroll
        for (int k = 16; k < 32; ++k) {
            const float hk = rlane(h1_own, k);
            g0b += hk * whh1_0[k];
            g1b += hk * whh1_1[k];
        }
        const float gr0 = ep0 + g0a + g0b;
        const float gr1 = ep1 + g1a + g1b;

        const float A0 = fsigm(gr0);                                            // i (h0) / f (h1)
        const float A1 = 1.0f - c1p * __builtin_amdgcn_rcpf(1.0f + __expf(a1 * gr1)); // g / o

        const float B0 = __shfl_xor(A0, 32);
        const float B1 = __shfl_xor(A1, 32);
        const float gi = half ? B0 : A0;
        const float gf = half ? A0 : B0;
        const float gg = half ? B1 : A1;
        const float go = half ? A1 : B1;

        c1 = gf * c1 + gi * gg;
        h1_own = go * ftanh(c1);

        // ---- layer 2 gates: bias + W_ih2 @ h1 + W_hh2 @ h2 ----
        float q0a = 0.0f, q0b = 0.0f, q1a = 0.0f, q1b = 0.0f;
#pragma unroll
        for (int k = 0; k < 32; ++k) {
            const float hk = rlane(h1_own, k);
            q0a += hk * wih2_0[k];
            q1a += hk * wih2_1[k];
        }
#pragma unroll
        for (int k = 0; k < 32; ++k) {
            const float pk = rlane(h2_own, k);
            q0b += pk * whh2_0[k];
            q1b += pk * whh2_1[k];
        }
        const float qr0 = bias20 + q0a + q0b;
        const float qr1 = bias21 + q1a + q1b;

        const float C0 = fsigm(qr0);
        const float C1 = 1.0f - c1p * __builtin_amdgcn_rcpf(1.0f + __expf(a1 * qr1));

        const float D0 = __shfl_xor(C0, 32);
        const float D1 = __shfl_xor(C1, 32);
        const float pi = half ? D0 : C0;
        const float pf = half ? C0 : D0;
        const float pg = half ? D1 : C1;
        const float po = half ? C1 : D1;

        c2 = pf * c2 + pi * pg;
        h2_own = po * ftanh(c2);

        if (l < HH) h2out[t * HH] = h2_own;

        ep0 = ep0n; ep1 = ep1n; idn = idn2;
    }
}

// ---------------------------------------------------------------------------
// Kernel C: logits = h2 @ W_fc^T + b_fc, row softmax, write [B*S][V].
// ---------------------------------------------------------------------------
__global__ __launch_bounds__(256) void fc_softmax_kernel(
    const float* __restrict__ h2_all, const float* __restrict__ W_fcT,
    const float* __restrict__ b_fc, float* __restrict__ out)
{
    const int tid = threadIdx.x;
    const long rowbase = (long)blockIdx.x * 8;
    __shared__ __align__(16) float h2t[8][HH];
    __shared__ float wred[8][4];

    h2t[tid >> 5][tid & 31] = h2_all[rowbase * HH + tid];
    __syncthreads();

    const int v0 = tid * 8;
    const float4 bf0 = *(const float4*)&b_fc[v0];
    const float4 bf1 = *(const float4*)&b_fc[v0 + 4];
    float acc[8][8];
#pragma unroll
    for (int r = 0; r < 8; ++r) {
        acc[r][0] = bf0.x; acc[r][1] = bf0.y; acc[r][2] = bf0.z; acc[r][3] = bf0.w;
        acc[r][4] = bf1.x; acc[r][5] = bf1.y; acc[r][6] = bf1.z; acc[r][7] = bf1.w;
    }

#pragma unroll
    for (int kq = 0; kq < 8; ++kq) {
        const int k = kq * 4;
        float4 wa[4], wb[4];
#pragma unroll
        for (int i = 0; i < 4; ++i) {
            wa[i] = *(const float4*)&W_fcT[(k + i) * VV + v0];
            wb[i] = *(const float4*)&W_fcT[(k + i) * VV + v0 + 4];
        }
#pragma unroll
        for (int r = 0; r < 8; ++r) {
            const float4 h = *(const float4*)&h2t[r][k];
            const float hh[4] = {h.x, h.y, h.z, h.w};
#pragma unroll
            for (int i = 0; i < 4; ++i) {
                acc[r][0] += hh[i] * wa[i].x; acc[r][1] += hh[i] * wa[i].y;
                acc[r][2] += hh[i] * wa[i].z; acc[r][3] += hh[i] * wa[i].w;
                acc[r][4] += hh[i] * wb[i].x; acc[r][5] += hh[i] * wb[i].y;
                acc[r][6] += hh[i] * wb[i].z; acc[r][7] += hh[i] * wb[i].w;
            }
        }
    }

    const int wv = tid >> 6;
    const int lane = tid & 63;

    float m[8];
#pragma unroll
    for (int r = 0; r < 8; ++r) {
        float v = acc[r][0];
#pragma unroll
        for (int c = 1; c < 8; ++c) v = fmaxf(v, acc[r][c]);
#pragma unroll
        for (int s = 32; s >= 1; s >>= 1) v = fmaxf(v, __shfl_xor(v, s, 64));
        m[r] = v;
    }
    if (lane == 0) {
#pragma unroll
        for (int r = 0; r < 8; ++r) wred[r][wv] = m[r];
    }
    __syncthreads();
    float rm[8];
#pragma unroll
    for (int r = 0; r < 8; ++r)
        rm[r] = fmaxf(fmaxf(wred[r][0], wred[r][1]), fmaxf(wred[r][2], wred[r][3]));
    __syncthreads();

    float s[8];
#pragma unroll
    for (int r = 0; r < 8; ++r) {
        float sum = 0.0f;
#pragma unroll
        for (int c = 0; c < 8; ++c) {
            float e = __expf(acc[r][c] - rm[r]);
            acc[r][c] = e;
            sum += e;
        }
#pragma unroll
        for (int st = 32; st >= 1; st >>= 1) sum += __shfl_xor(sum, st, 64);
        s[r] = sum;
    }
    if (lane == 0) {
#pragma unroll
        for (int r = 0; r < 8; ++r) wred[r][wv] = s[r];
    }
    __syncthreads();

#pragma unroll
    for (int r = 0; r < 8; ++r) {
        const float rs = wred[r][0] + wred[r][1] + wred[r][2] + wred[r][3];
        const float inv = 1.0f / rs;
        float4 o0 = make_float4(acc[r][0] * inv, acc[r][1] * inv, acc[r][2] * inv, acc[r][3] * inv);
        float4 o1 = make_float4(acc[r][4] * inv, acc[r][5] * inv, acc[r][6] * inv, acc[r][7] * inv);
        float* op = out + (rowbase + r) * VV + v0;
        *(float4*)op = o0;
        *(float4*)(op + 4) = o1;
    }
}

// ---------------------------------------------------------------------------
extern "C" void kernel_launch(void* const* d_in, const int* in_sizes, int n_in,
                              void* d_out, int out_size, void* d_ws, size_t ws_size,
                              hipStream_t stream)
{
    const int*   x_ids = (const int*)d_in[0];
    const float* emb   = (const float*)d_in[1];
    const float* W_ih1 = (const float*)d_in[2];
    const float* W_hh1 = (const float*)d_in[3];
    const float* b_ih1 = (const float*)d_in[4];
    const float* b_hh1 = (const float*)d_in[5];
    const float* W_ih2 = (const float*)d_in[6];
    const float* W_hh2 = (const float*)d_in[7];
    const float* b_ih2 = (const float*)d_in[8];
    const float* b_hh2 = (const float*)d_in[9];
    const float* W_fc  = (const float*)d_in[10];
    const float* b_fc  = (const float*)d_in[11];
    float* out = (float*)d_out;

    float* ws = (float*)d_ws;
    float* emb_proj = ws;                         // V*4H   = 262144
    float* W_fcT    = ws + 262144;                // H*V    = 65536
    float* h2_all   = ws + 262144 + 65536;        // B*S*H  = 2097152

    emb_proj_kernel<<<VV, 128, 0, stream>>>(emb, W_ih1, b_ih1, b_hh1, emb_proj);
    transpose_wfc_kernel<<<(VV * HH) / 256, 256, 0, stream>>>(W_fc, W_fcT);
    lstm_rec_wave_kernel<<<BB, 64, 0, stream>>>(x_ids, emb_proj, W_hh1, W_ih2, W_hh2,
                                                b_ih2, b_hh2, h2_all);
    fc_softmax_kernel<<<(BB * SEQ) / 8, 256, 0, stream>>>(h2_all, W_fcT, b_fc, out);
}

// Round 5
// 1214.698 us; speedup vs baseline: 1.1128x; 1.0596x over previous
//
#include <hip/hip_runtime.h>
#include <cmath>

#define BB   64
#define SEQ  1024
#define DD   256
#define HH   32
#define G4   128   // 4*H
#define VV   2048

// fast sigmoid: exact form e^x/(1+e^x) = 1 - 1/(1+e^x)
__device__ __forceinline__ float fsigm(float x) {
    return 1.0f - __builtin_amdgcn_rcpf(1.0f + __expf(x));
}
// fast tanh: 1 - 2/(1+e^(2x))
__device__ __forceinline__ float ftanh(float x) {
    return 1.0f - 2.0f * __builtin_amdgcn_rcpf(1.0f + __expf(2.0f * x));
}

// ---- named-variable helpers: NO local arrays, NO pointer escapes ----------
#define DECL8(p)  float4 p##0, p##1, p##2, p##3, p##4, p##5, p##6, p##7

#define LOADW(p, base, row) do {                                         \
    const float4* _q = (const float4*)&(base)[(row) * HH];               \
    p##0 = _q[0]; p##1 = _q[1]; p##2 = _q[2]; p##3 = _q[3];              \
    p##4 = _q[4]; p##5 = _q[5]; p##6 = _q[6]; p##7 = _q[7];              \
} while (0)

#define LOADH(h, src) do {                                               \
    h##0 = (src)[0]; h##1 = (src)[1]; h##2 = (src)[2]; h##3 = (src)[3]; \
    h##4 = (src)[4]; h##5 = (src)[5]; h##6 = (src)[6]; h##7 = (src)[7]; \
} while (0)

#define ZERO8(h) do {                                                    \
    h##0 = h##1 = h##2 = h##3 = h##4 = h##5 = h##6 = h##7 =              \
        make_float4(0.f, 0.f, 0.f, 0.f);                                 \
} while (0)

#define FMA4(acc, wq, hq)                                                \
    acc = fmaf(wq.w, hq.w, fmaf(wq.z, hq.z, fmaf(wq.y, hq.y, fmaf(wq.x, hq.x, acc))))

// 32-long dot over named float4s, 4 independent accumulator chains
#define DOT32(res, w, h) do {                                            \
    float _a0 = 0.f, _a1 = 0.f, _a2 = 0.f, _a3 = 0.f;                    \
    FMA4(_a0, w##0, h##0); FMA4(_a1, w##1, h##1);                        \
    FMA4(_a2, w##2, h##2); FMA4(_a3, w##3, h##3);                        \
    FMA4(_a0, w##4, h##4); FMA4(_a1, w##5, h##5);                        \
    FMA4(_a2, w##6, h##6); FMA4(_a3, w##7, h##7);                        \
    res = (_a0 + _a1) + (_a2 + _a3);                                     \
} while (0)

// ---------------------------------------------------------------------------
// Kernel A1: emb_proj[v][j] = b_ih1[j] + b_hh1[j] + sum_d emb[v][d] * W_ih1[j][d]
// ---------------------------------------------------------------------------
__global__ __launch_bounds__(128) void emb_proj_kernel(
    const float* __restrict__ emb, const float* __restrict__ W_ih1,
    const float* __restrict__ b_ih1, const float* __restrict__ b_hh1,
    float* __restrict__ emb_proj)
{
    const int v = blockIdx.x;
    const int j = threadIdx.x;
    __shared__ __align__(16) float ev[DD];
    ev[j]       = emb[v * DD + j];
    ev[j + 128] = emb[v * DD + 128 + j];
    __syncthreads();
    float acc = b_ih1[j] + b_hh1[j];
#pragma unroll 8
    for (int q = 0; q < DD / 4; ++q) {
        float4 w = *(const float4*)&W_ih1[j * DD + 4 * q];
        float4 e = *(const float4*)&ev[4 * q];
        acc += w.x * e.x + w.y * e.y + w.z * e.z + w.w * e.w;
    }
    emb_proj[v * G4 + j] = acc;
}

// ---------------------------------------------------------------------------
// Kernel A2: W_fcT[k][v] = W_fc[v][k]
// ---------------------------------------------------------------------------
__global__ __launch_bounds__(256) void transpose_wfc_kernel(
    const float* __restrict__ W_fc, float* __restrict__ W_fcT)
{
    int i = blockIdx.x * 256 + threadIdx.x;
    int v = i >> 5;
    int k = i & 31;
    W_fcT[k * VV + v] = W_fc[i];
}

// ---------------------------------------------------------------------------
// Kernel B: 2-layer LSTM recurrence, one wave per batch element.
// Lane l owns gate rows r0=l and r1=l+64 (rows 0-31 i, 32-63 f, 64-95 g,
// 96-127 o). All weights/states are NAMED variables (no arrays, no pointer
// escapes -> clean SSA -> register-resident). h1/h2 broadcast via LDS write
// + uniform ds_read_b128; the h1 read latency hides under the W_hh2*h2 dots.
// ---------------------------------------------------------------------------
__global__ __launch_bounds__(64, 1) void lstm_rec_wave_kernel(
    const int* __restrict__ x_ids, const float* __restrict__ emb_proj,
    const float* __restrict__ W_hh1, const float* __restrict__ W_ih2,
    const float* __restrict__ W_hh2, const float* __restrict__ b_ih2,
    const float* __restrict__ b_hh2, float* __restrict__ h2_all)
{
    const int b = blockIdx.x;
    const int l = threadIdx.x;      // 0..63
    const int half = l >> 5;
    const int r0 = l;
    const int r1 = l + 64;

    // r0 rows (i or f): sigmoid. r1 rows: g (tanh) on half0, o (sigm) on half1.
    const float a1  = half ? 1.0f : 2.0f;   // exp argument scale
    const float c1p = half ? 1.0f : 2.0f;   // rcp coefficient

    DECL8(w11a); DECL8(w11b); DECL8(w21a); DECL8(w21b); DECL8(w22a); DECL8(w22b);
    LOADW(w11a, W_hh1, r0); LOADW(w11b, W_hh1, r1);
    LOADW(w21a, W_ih2, r0); LOADW(w21b, W_ih2, r1);
    LOADW(w22a, W_hh2, r0); LOADW(w22b, W_hh2, r1);

    const float bias20 = b_ih2[r0] + b_hh2[r0];
    const float bias21 = b_ih2[r1] + b_hh2[r1];

    __shared__ __align__(16) float h1s[HH];
    __shared__ __align__(16) float h2s[HH];
    const float4* h1v = (const float4*)h1s;
    const float4* h2v = (const float4*)h2s;

    DECL8(h1q); DECL8(h2q);
    ZERO8(h1q); ZERO8(h2q);

    float c1 = 0.0f, c2 = 0.0f;

    const int* ids = x_ids + b * SEQ;
    int idn = ids[1];
    float ep0 = emb_proj[ids[0] * G4 + r0];
    float ep1 = emb_proj[ids[0] * G4 + r1];

    float* h2out = h2_all + (long)b * SEQ * HH + l;

    for (int t = 0; t < SEQ; ++t) {
        // prefetch next step's emb_proj row + id two steps ahead (hidden)
        const float ep0n = emb_proj[idn * G4 + r0];
        const float ep1n = emb_proj[idn * G4 + r1];
        const int tn2 = (t + 2 < SEQ) ? (t + 2) : (SEQ - 1);
        const int idn2 = ids[tn2];

        // ---- layer 1 gates: ep + W_hh1 @ h1(prev) ----
        float d0, d1;
        DOT32(d0, w11a, h1q);
        DOT32(d1, w11b, h1q);
        const float gr0 = ep0 + d0;
        const float gr1 = ep1 + d1;

        const float A0 = fsigm(gr0);
        const float A1 = 1.0f - c1p * __builtin_amdgcn_rcpf(1.0f + __expf(a1 * gr1));
        const float B0 = __shfl_xor(A0, 32, 64);
        const float B1 = __shfl_xor(A1, 32, 64);
        const float gi = half ? B0 : A0;
        const float gf = half ? A0 : B0;
        const float gg = half ? B1 : A1;
        const float go = half ? A1 : B1;

        c1 = gf * c1 + gi * gg;
        const float h1n = go * ftanh(c1);

        // publish h1, immediately issue the broadcast reads (latency hidden
        // under the independent W_hh2 @ h2(prev) dots below)
        if (l < HH) h1s[l] = h1n;
        LOADH(h1q, h1v);

        float p0, p1;
        DOT32(p0, w22a, h2q);
        DOT32(p1, w22b, h2q);

        // ---- layer 2 gates ----
        float e0, e1;
        DOT32(e0, w21a, h1q);
        DOT32(e1, w21b, h1q);
        const float qr0 = bias20 + p0 + e0;
        const float qr1 = bias21 + p1 + e1;

        const float C0 = fsigm(qr0);
        const float C1 = 1.0f - c1p * __builtin_amdgcn_rcpf(1.0f + __expf(a1 * qr1));
        const float D0 = __shfl_xor(C0, 32, 64);
        const float D1 = __shfl_xor(C1, 32, 64);
        const float pi = half ? D0 : C0;
        const float pf = half ? C0 : D0;
        const float pg = half ? D1 : C1;
        const float po = half ? C1 : D1;

        c2 = pf * c2 + pi * pg;
        const float h2n = po * ftanh(c2);

        if (l < HH) { h2s[l] = h2n; h2out[t * HH] = h2n; }
        // broadcast h2 for next step (latency hides under next layer-1 dots)
        LOADH(h2q, h2v);

        ep0 = ep0n; ep1 = ep1n; idn = idn2;
    }
}

// ---------------------------------------------------------------------------
// Kernel C: logits = h2 @ W_fc^T + b_fc, row softmax, write [B*S][V].
// 16 rows per block, 256 threads, thread owns 8 contiguous vocab cols.
// ---------------------------------------------------------------------------
__global__ __launch_bounds__(256, 1) void fc_softmax_kernel(
    const float* __restrict__ h2_all, const float* __restrict__ W_fcT,
    const float* __restrict__ b_fc, float* __restrict__ out)
{
    const int tid = threadIdx.x;
    const long rowbase = (long)blockIdx.x * 16;
    __shared__ __align__(16) float h2t[16][HH];
    __shared__ float wred[16][4];

    ((float*)h2t)[tid]       = h2_all[rowbase * HH + tid];
    ((float*)h2t)[tid + 256] = h2_all[rowbase * HH + tid + 256];
    __syncthreads();

    const int v0 = tid * 8;
    const float4 bf0 = *(const float4*)&b_fc[v0];
    const float4 bf1 = *(const float4*)&b_fc[v0 + 4];
    float acc[16][8];
#pragma unroll
    for (int r = 0; r < 16; ++r) {
        acc[r][0] = bf0.x; acc[r][1] = bf0.y; acc[r][2] = bf0.z; acc[r][3] = bf0.w;
        acc[r][4] = bf1.x; acc[r][5] = bf1.y; acc[r][6] = bf1.z; acc[r][7] = bf1.w;
    }

#pragma unroll
    for (int kq = 0; kq < 8; ++kq) {
        const int k = kq * 4;
        float4 wa[4], wb[4];
#pragma unroll
        for (int i = 0; i < 4; ++i) {
            wa[i] = *(const float4*)&W_fcT[(k + i) * VV + v0];
            wb[i] = *(const float4*)&W_fcT[(k + i) * VV + v0 + 4];
        }
#pragma unroll
        for (int r = 0; r < 16; ++r) {
            const float4 h = *(const float4*)&h2t[r][k];
            const float hh[4] = {h.x, h.y, h.z, h.w};
#pragma unroll
            for (int i = 0; i < 4; ++i) {
                acc[r][0] += hh[i] * wa[i].x; acc[r][1] += hh[i] * wa[i].y;
                acc[r][2] += hh[i] * wa[i].z; acc[r][3] += hh[i] * wa[i].w;
                acc[r][4] += hh[i] * wb[i].x; acc[r][5] += hh[i] * wb[i].y;
                acc[r][6] += hh[i] * wb[i].z; acc[r][7] += hh[i] * wb[i].w;
            }
        }
    }

    const int wv = tid >> 6;
    const int lane = tid & 63;

    float m[16];
#pragma unroll
    for (int r = 0; r < 16; ++r) {
        float v = acc[r][0];
#pragma unroll
        for (int c = 1; c < 8; ++c) v = fmaxf(v, acc[r][c]);
#pragma unroll
        for (int s = 32; s >= 1; s >>= 1) v = fmaxf(v, __shfl_xor(v, s, 64));
        m[r] = v;
    }
    if (lane == 0) {
#pragma unroll
        for (int r = 0; r < 16; ++r) wred[r][wv] = m[r];
    }
    __syncthreads();
    float rm[16];
#pragma unroll
    for (int r = 0; r < 16; ++r)
        rm[r] = fmaxf(fmaxf(wred[r][0], wred[r][1]), fmaxf(wred[r][2], wred[r][3]));
    __syncthreads();

    float s[16];
#pragma unroll
    for (int r = 0; r < 16; ++r) {
        float sum = 0.0f;
#pragma unroll
        for (int c = 0; c < 8; ++c) {
            float e = __expf(acc[r][c] - rm[r]);
            acc[r][c] = e;
            sum += e;
        }
#pragma unroll
        for (int st = 32; st >= 1; st >>= 1) sum += __shfl_xor(sum, st, 64);
        s[r] = sum;
    }
    if (lane == 0) {
#pragma unroll
        for (int r = 0; r < 16; ++r) wred[r][wv] = s[r];
    }
    __syncthreads();

#pragma unroll
    for (int r = 0; r < 16; ++r) {
        const float rs = wred[r][0] + wred[r][1] + wred[r][2] + wred[r][3];
        const float inv = 1.0f / rs;
        float4 o0 = make_float4(acc[r][0] * inv, acc[r][1] * inv, acc[r][2] * inv, acc[r][3] * inv);
        float4 o1 = make_float4(acc[r][4] * inv, acc[r][5] * inv, acc[r][6] * inv, acc[r][7] * inv);
        float* op = out + (rowbase + r) * VV + v0;
        *(float4*)op = o0;
        *(float4*)(op + 4) = o1;
    }
}

// ---------------------------------------------------------------------------
extern "C" void kernel_launch(void* const* d_in, const int* in_sizes, int n_in,
                              void* d_out, int out_size, void* d_ws, size_t ws_size,
                              hipStream_t stream)
{
    const int*   x_ids = (const int*)d_in[0];
    const float* emb   = (const float*)d_in[1];
    const float* W_ih1 = (const float*)d_in[2];
    const float* W_hh1 = (const float*)d_in[3];
    const float* b_ih1 = (const float*)d_in[4];
    const float* b_hh1 = (const float*)d_in[5];
    const float* W_ih2 = (const float*)d_in[6];
    const float* W_hh2 = (const float*)d_in[7];
    const float* b_ih2 = (const float*)d_in[8];
    const float* b_hh2 = (const float*)d_in[9];
    const float* W_fc  = (const float*)d_in[10];
    const float* b_fc  = (const float*)d_in[11];
    float* out = (float*)d_out;

    float* ws = (float*)d_ws;
    float* emb_proj = ws;                         // V*4H   = 262144
    float* W_fcT    = ws + 262144;                // H*V    = 65536
    float* h2_all   = ws + 262144 + 65536;        // B*S*H  = 2097152

    emb_proj_kernel<<<VV, 128, 0, stream>>>(emb, W_ih1, b_ih1, b_hh1, emb_proj);
    transpose_wfc_kernel<<<(VV * HH) / 256, 256, 0, stream>>>(W_fc, W_fcT);
    lstm_rec_wave_kernel<<<BB, 64, 0, stream>>>(x_ids, emb_proj, W_hh1, W_ih2, W_hh2,
                                                b_ih2, b_hh2, h2_all);
    fc_softmax_kernel<<<(BB * SEQ) / 16, 256, 0, stream>>>(h2_all, W_fcT, b_fc, out);
}